// Round 8
// baseline (769.749 us; speedup 1.0000x reference)
//
#include <hip/hip_runtime.h>

#define NTOK 49
#define HEADS 6
#define CDIM 192
#define NWIN 4096

typedef unsigned short u16;
typedef unsigned int u32;
typedef unsigned long long u64;
typedef __attribute__((ext_vector_type(8))) __bf16 bf16x8;
typedef __attribute__((ext_vector_type(4))) float floatx4;
typedef __attribute__((ext_vector_type(4))) u32 u32x4;

struct __attribute__((aligned(4))) F4 { float f[4]; };

// LDS layout (bytes), 16-wave block (1024 thr), 1 block/CU.
#define OFF_X 0         // [64][200] u16 (X, later AO)          25600
#define OFF_Q 25600     // [64][200] u16 (raw Q)                25600
#define OFF_K 51200     // [64][200] u16 (raw K)                25600
#define OFF_V 76800     // [192][72] u16  Vt[chan][tok]         27648
#define OFF_P 104448    // [12 waves][16][72] u16               27648
#define OFF_N 132096    // [12 waves][128] f32 (krec|qrec)       6144
#define LDS_BYTES 138240

__device__ __forceinline__ u16 f2bf(float f) {
  return __builtin_bit_cast(u16, (__bf16)f);
}
__device__ __forceinline__ void st4bf(u16* p, float a, float b, float c, float d) {
  u32 lo = (u32)f2bf(a) | ((u32)f2bf(b) << 16);
  u32 hi = (u32)f2bf(c) | ((u32)f2bf(d) << 16);
  u64 t = (u64)lo | ((u64)hi << 32);
  *(u64*)p = t;
}
__device__ __forceinline__ float bflo(u32 u) {
  union { u32 u; float f; } v; v.u = u << 16;
  return v.f;
}
__device__ __forceinline__ float bfhi(u32 u) {
  union { u32 u; float f; } v; v.u = u & 0xffff0000u;
  return v.f;
}

__global__ __launch_bounds__(256)
void wprep(const float* __restrict__ Wq, const float* __restrict__ Wk,
           const float* __restrict__ Wv, const float* __restrict__ Wp,
           const float* __restrict__ rpb, const int* __restrict__ rel,
           u16* __restrict__ w_bf, float* __restrict__ bias) {
  const int tid = blockIdx.x * blockDim.x + threadIdx.x;
  const int stride = gridDim.x * blockDim.x;
  for (int i = tid; i < 4 * CDIM * CDIM; i += stride) {
    const int p = i / (CDIM * CDIM), e = i % (CDIM * CDIM);
    float v = (p == 0) ? Wq[e] : (p == 1) ? Wk[e] : (p == 2) ? Wv[e] : Wp[e];
    w_bf[i] = f2bf(v);
  }
  for (int i = tid; i < HEADS * NTOK * NTOK; i += stride) {
    const int h = i / (NTOK * NTOK), nm = i % (NTOK * NTOK);
    bias[i] = rpb[rel[nm] * HEADS + h];
  }
}

// Fused window attention: 16 waves; half-split cached fragments; norm folded into softmax.
__global__ __launch_bounds__(1024)
void wattn_main(const float* __restrict__ x, const float* __restrict__ mask,
                const float* __restrict__ d_l, const float* __restrict__ temp,
                const u16* __restrict__ w_bf, const float* __restrict__ bias,
                float* __restrict__ out) {
  extern __shared__ __align__(16) char smem[];
  u16* Xb = (u16*)(smem + OFF_X);
  u16* Qn = (u16*)(smem + OFF_Q);
  u16* Kn = (u16*)(smem + OFF_K);
  u16* Vt = (u16*)(smem + OFF_V);
  u16* Pw = (u16*)(smem + OFF_P);

  const int b = blockIdx.x;
  const int tid = threadIdx.x;
  const int wave = tid >> 6;   // 0..15
  const int lane = tid & 63;
  const int g = lane >> 4;
  const int nl = lane & 15;
  const int half = wave & 1;

  // ---- phase 0: stage x -> bf16 LDS [64][200], zero pad rows 49..63
  {
    const float* xb = x + (size_t)b * (NTOK * CDIM);
    for (int i = tid; i < NTOK * 48; i += 1024) {
      const int n = i / 48;
      const int c = (i - n * 48) * 4;
      const float4 v = *(const float4*)(xb + n * CDIM + c);
      st4bf(Xb + n * 200 + c, v.x, v.y, v.z, v.w);
    }
    if (tid < 15 * 48) {
      const int n = NTOK + tid / 48;
      const int c = (tid % 48) * 4;
      *(u64*)(Xb + n * 200 + c) = 0ull;
    }
  }
  __syncthreads();

  // ---- phase 1: QKV. 72 half-subtasks over 16 waves; xf[2][6] cached per wave.
  {
    bf16x8 xf[2][6];
#pragma unroll
    for (int nt2 = 0; nt2 < 2; ++nt2)
#pragma unroll
      for (int k = 0; k < 6; ++k)
        xf[nt2][k] = *(const bf16x8*)(Xb + (half * 32 + nt2 * 16 + nl) * 200 + k * 32 + g * 8);

    for (int t = wave >> 1; t < 36; t += 8) {
      const int p = t / 12, o = t - p * 12;
      const u16* wb = w_bf + p * (CDIM * CDIM) + (o * 16 + nl) * CDIM + g * 8;
      floatx4 acc[2];
      acc[0] = (floatx4){0.f, 0.f, 0.f, 0.f};
      acc[1] = (floatx4){0.f, 0.f, 0.f, 0.f};
      if (p < 2) {
#pragma unroll
        for (int k = 0; k < 6; ++k) {
          const bf16x8 wf = *(const bf16x8*)(wb + k * 32);
          acc[0] = __builtin_amdgcn_mfma_f32_16x16x32_bf16(wf, xf[0][k], acc[0], 0, 0, 0);
          acc[1] = __builtin_amdgcn_mfma_f32_16x16x32_bf16(wf, xf[1][k], acc[1], 0, 0, 0);
        }
        u16* dst = (p == 0 ? Qn : Kn);
#pragma unroll
        for (int nt2 = 0; nt2 < 2; ++nt2)
          st4bf(dst + (half * 32 + nt2 * 16 + nl) * 200 + o * 16 + g * 4,
                acc[nt2][0], acc[nt2][1], acc[nt2][2], acc[nt2][3]);
      } else {
#pragma unroll
        for (int k = 0; k < 6; ++k) {
          const bf16x8 wf = *(const bf16x8*)(wb + k * 32);
          acc[0] = __builtin_amdgcn_mfma_f32_16x16x32_bf16(xf[0][k], wf, acc[0], 0, 0, 0);
          acc[1] = __builtin_amdgcn_mfma_f32_16x16x32_bf16(xf[1][k], wf, acc[1], 0, 0, 0);
        }
#pragma unroll
        for (int nt2 = 0; nt2 < 2; ++nt2)
          st4bf(Vt + (o * 16 + nl) * 72 + half * 32 + nt2 * 16 + g * 4,
                acc[nt2][0], acc[nt2][1], acc[nt2][2], acc[nt2][3]);
      }
    }
  }
  __syncthreads();

  // ---- phase 3: attention; norm folded into scale (R4 formula). 12 waves, kf cached.
  if (wave < 12) {
    const int h = wave >> 1;
    float* nrmw = (float*)(smem + OFF_N) + wave * 128;
    // per-wave norms: lane = token; same-wave LDS write->read (no barrier needed)
    {
      float ssk = 0.f, ssq = 0.f;
      const u16* krow = Kn + lane * 200 + h * 32;
      const u16* qrow = Qn + lane * 200 + h * 32;
#pragma unroll
      for (int j = 0; j < 4; ++j) {
        const u32x4 kk = *(const u32x4*)(krow + j * 8);
        const u32x4 qq = *(const u32x4*)(qrow + j * 8);
#pragma unroll
        for (int e = 0; e < 4; ++e) {
          const float k0 = bflo(kk[e]), k1 = bfhi(kk[e]);
          const float q0 = bflo(qq[e]), q1 = bfhi(qq[e]);
          ssk = fmaf(k0, k0, fmaf(k1, k1, ssk));
          ssq = fmaf(q0, q0, fmaf(q1, q1, ssq));
        }
      }
      nrmw[lane] = 1.f / fmaxf(sqrtf(ssk), 1e-12f);
      nrmw[64 + lane] = 1.f / fmaxf(sqrtf(ssq), 1e-12f);
    }
    const float dl = d_l[b];
    const float LOG2E = 1.442695040888963f;
    const float dl2 = dl * LOG2E;
    const float tdl = temp[h] * dl2;
    const int wmask = b & (NWIN - 1);
    u16* Pb = Pw + wave * (16 * 72);
    bf16x8 kf[4];
#pragma unroll
    for (int rt = 0; rt < 4; ++rt)
      kf[rt] = *(const bf16x8*)(Kn + (rt * 16 + nl) * 200 + h * 32 + g * 8);

#pragma unroll
    for (int j = 0; j < 2; ++j) {
      const int nt2 = (wave & 1) * 2 + j;
      const int n = nt2 * 16 + nl;
      const int ncl = n < NTOK ? n : NTOK - 1;
      const bf16x8 qf = *(const bf16x8*)(Qn + n * 200 + h * 32 + g * 8);
      floatx4 sacc[4];
#pragma unroll
      for (int rt = 0; rt < 4; ++rt)
        sacc[rt] = __builtin_amdgcn_mfma_f32_16x16x32_bf16(kf[rt], qf, (floatx4){0.f, 0.f, 0.f, 0.f}, 0, 0, 0);
      const float qr2 = nrmw[64 + n] * tdl;
      const float* brow = bias + (h * NTOK + ncl) * NTOK;
      const float* mrow = mask + ((size_t)wmask * NTOK + ncl) * NTOK;
      float L[4][4];
      float pmax = -1e30f;
#pragma unroll
      for (int rt = 0; rt < 3; ++rt) {
        const F4 b4 = *(const F4*)(brow + rt * 16 + g * 4);
        const F4 m4 = *(const F4*)(mrow + rt * 16 + g * 4);
        const F4 kr = *(const F4*)(nrmw + rt * 16 + g * 4);
#pragma unroll
        for (int r = 0; r < 4; ++r) {
          const float lv = fmaf(sacc[rt][r] * kr.f[r], qr2, (b4.f[r] + m4.f[r]) * dl2);
          L[rt][r] = lv;
          pmax = fmaxf(pmax, lv);
        }
      }
      {  // rt=3: only m=48 real (g==0, r==0)
        const float lv48 = fmaf(sacc[3][0] * nrmw[48], qr2, (brow[48] + mrow[48]) * dl2);
        L[3][0] = L[3][1] = L[3][2] = L[3][3] = -1e30f;
        if (g == 0) { L[3][0] = lv48; pmax = fmaxf(pmax, lv48); }
      }
      pmax = fmaxf(pmax, __shfl_xor(pmax, 16));
      pmax = fmaxf(pmax, __shfl_xor(pmax, 32));
      float psum = 0.f;
#pragma unroll
      for (int rt = 0; rt < 4; ++rt)
#pragma unroll
        for (int r = 0; r < 4; ++r) {
          const float e = exp2f(L[rt][r] - pmax);
          L[rt][r] = e;
          psum += e;
        }
      psum += __shfl_xor(psum, 16);
      psum += __shfl_xor(psum, 32);
      const float rinv = 1.0f / psum;
#pragma unroll
      for (int rt = 0; rt < 4; ++rt)
        st4bf(Pb + nl * 72 + rt * 16 + g * 4,
              L[rt][0] * rinv, L[rt][1] * rinv, L[rt][2] * rinv, L[rt][3] * rinv);
      floatx4 oacc[2];
      oacc[0] = (floatx4){0.f, 0.f, 0.f, 0.f};
      oacc[1] = (floatx4){0.f, 0.f, 0.f, 0.f};
#pragma unroll
      for (int ks = 0; ks < 2; ++ks) {
        const bf16x8 pf = *(const bf16x8*)(Pb + nl * 72 + ks * 32 + g * 8);
#pragma unroll
        for (int dt = 0; dt < 2; ++dt) {
          const bf16x8 vf = *(const bf16x8*)(Vt + (h * 32 + dt * 16 + nl) * 72 + ks * 32 + g * 8);
          oacc[dt] = __builtin_amdgcn_mfma_f32_16x16x32_bf16(vf, pf, oacc[dt], 0, 0, 0);
        }
      }
#pragma unroll
      for (int dt = 0; dt < 2; ++dt)
        st4bf(Xb + n * 200 + h * 32 + dt * 16 + g * 4,
              oacc[dt][0], oacc[dt][1], oacc[dt][2], oacc[dt][3]);
    }
  }
  __syncthreads();

  // ---- phase 4: out = AO @ Wp^T; 24 half-subtasks over 16 waves; af[2][6] cached.
  {
    bf16x8 af[2][6];
#pragma unroll
    for (int nt2 = 0; nt2 < 2; ++nt2)
#pragma unroll
      for (int k = 0; k < 6; ++k)
        af[nt2][k] = *(const bf16x8*)(Xb + (half * 32 + nt2 * 16 + nl) * 200 + k * 32 + g * 8);
    float* outb = out + (size_t)b * (NTOK * CDIM);
    const u16* wpb = w_bf + 3 * (CDIM * CDIM);
    for (int s = wave; s < 24; s += 16) {
      const int o = s >> 1;
      const u16* wb = wpb + (o * 16 + nl) * CDIM + g * 8;
      floatx4 acc[2];
      acc[0] = (floatx4){0.f, 0.f, 0.f, 0.f};
      acc[1] = (floatx4){0.f, 0.f, 0.f, 0.f};
#pragma unroll
      for (int k = 0; k < 6; ++k) {
        const bf16x8 wf = *(const bf16x8*)(wb + k * 32);
        acc[0] = __builtin_amdgcn_mfma_f32_16x16x32_bf16(wf, af[0][k], acc[0], 0, 0, 0);
        acc[1] = __builtin_amdgcn_mfma_f32_16x16x32_bf16(wf, af[1][k], acc[1], 0, 0, 0);
      }
#pragma unroll
      for (int nt2 = 0; nt2 < 2; ++nt2) {
        const int n = half * 32 + nt2 * 16 + nl;
        if (n < NTOK) {
          float4 v;
          v.x = acc[nt2][0]; v.y = acc[nt2][1]; v.z = acc[nt2][2]; v.w = acc[nt2][3];
          *(float4*)(outb + n * CDIM + o * 16 + g * 4) = v;
        }
      }
    }
  }
}

extern "C" void kernel_launch(void* const* d_in, const int* in_sizes, int n_in,
                              void* d_out, int out_size, void* d_ws, size_t ws_size,
                              hipStream_t stream) {
  const float* x    = (const float*)d_in[0];
  const float* mask = (const float*)d_in[1];
  const float* dl   = (const float*)d_in[2];
  const float* Wq   = (const float*)d_in[3];
  const float* Wk   = (const float*)d_in[4];
  const float* Wv   = (const float*)d_in[5];
  const float* Wp   = (const float*)d_in[6];
  const float* temp = (const float*)d_in[7];
  const float* rpb  = (const float*)d_in[8];
  const int*   rel  = (const int*)d_in[9];

  u16* w_bf = (u16*)d_ws;
  float* bias = (float*)((char*)d_ws + (size_t)4 * CDIM * CDIM * sizeof(u16));
  float* o = (float*)d_out;

  (void)hipFuncSetAttribute((const void*)wattn_main,
                            hipFuncAttributeMaxDynamicSharedMemorySize, LDS_BYTES);

  wprep<<<256, 256, 0, stream>>>(Wq, Wk, Wv, Wp, rpb, rel, w_bf, bias);
  wattn_main<<<8192, 1024, LDS_BYTES, stream>>>(x, mask, dl, temp, w_bf, bias, o);
}

// Round 9
// 628.471 us; speedup vs baseline: 1.2248x; 1.2248x over previous
//
#include <hip/hip_runtime.h>

#define NTOK 49
#define HEADS 6
#define CDIM 192
#define NWIN 4096

typedef unsigned short u16;
typedef unsigned int u32;
typedef unsigned long long u64;
typedef __attribute__((ext_vector_type(8))) __bf16 bf16x8;
typedef __attribute__((ext_vector_type(4))) float floatx4;

struct __attribute__((aligned(4))) F4 { float f[4]; };

// LDS layout (bytes), 16-wave block (1024 thr), 1 block/CU.
#define OFF_X 0         // [64][200] u16 (X, later AO)          25600
#define OFF_Q 25600     // [64][200] u16                        25600
#define OFF_K 51200     // [64][200] u16                        25600
#define OFF_V 76800     // [192][72] u16  Vt[chan][tok]         27648
#define OFF_P 104448    // [16 waves][16][72] u16               36864
#define LDS_BYTES 141312

__device__ __forceinline__ u16 f2bf(float f) {
  return __builtin_bit_cast(u16, (__bf16)f);
}
__device__ __forceinline__ void st4bf(u16* p, float a, float b, float c, float d) {
  u32 lo = (u32)f2bf(a) | ((u32)f2bf(b) << 16);
  u32 hi = (u32)f2bf(c) | ((u32)f2bf(d) << 16);
  u64 t = (u64)lo | ((u64)hi << 32);
  *(u64*)p = t;
}
__device__ __forceinline__ float bf2f(u16 u) {
  union { u32 u; float f; } v; v.u = ((u32)u) << 16;
  return v.f;
}

__global__ __launch_bounds__(256)
void wprep(const float* __restrict__ Wq, const float* __restrict__ Wk,
           const float* __restrict__ Wv, const float* __restrict__ Wp,
           const float* __restrict__ rpb, const int* __restrict__ rel,
           u16* __restrict__ w_bf, float* __restrict__ bias) {
  const int tid = blockIdx.x * blockDim.x + threadIdx.x;
  const int stride = gridDim.x * blockDim.x;
  for (int i = tid; i < 4 * CDIM * CDIM; i += stride) {
    const int p = i / (CDIM * CDIM), e = i % (CDIM * CDIM);
    float v = (p == 0) ? Wq[e] : (p == 1) ? Wk[e] : (p == 2) ? Wv[e] : Wp[e];
    w_bf[i] = f2bf(v);
  }
  for (int i = tid; i < HEADS * NTOK * NTOK; i += stride) {
    const int h = i / (NTOK * NTOK), nm = i % (NTOK * NTOK);
    bias[i] = rpb[rel[nm] * HEADS + h];
  }
}

// Fused window attention: 16 waves; o-triple wide tasks in phases 1/4 (12-wide MFMA ILP,
// 3x fewer LDS fragment re-reads); phases 0/2/3 = proven R7 code.
__global__ __launch_bounds__(1024)
void wattn_main(const float* __restrict__ x, const float* __restrict__ mask,
                const float* __restrict__ d_l, const float* __restrict__ temp,
                const u16* __restrict__ w_bf, const float* __restrict__ bias,
                float* __restrict__ out) {
  extern __shared__ __align__(16) char smem[];
  u16* Xb = (u16*)(smem + OFF_X);
  u16* Qn = (u16*)(smem + OFF_Q);
  u16* Kn = (u16*)(smem + OFF_K);
  u16* Vt = (u16*)(smem + OFF_V);
  u16* Pw = (u16*)(smem + OFF_P);

  const int b = blockIdx.x;
  const int tid = threadIdx.x;
  const int wave = tid >> 6;   // 0..15
  const int lane = tid & 63;
  const int g = lane >> 4;
  const int nl = lane & 15;

  // ---- phase 0: stage x -> bf16 LDS [64][200], zero pad rows 49..63
  {
    const float* xb = x + (size_t)b * (NTOK * CDIM);
    for (int i = tid; i < NTOK * 48; i += 1024) {
      const int n = i / 48;
      const int c = (i - n * 48) * 4;
      const float4 v = *(const float4*)(xb + n * CDIM + c);
      st4bf(Xb + n * 200 + c, v.x, v.y, v.z, v.w);
    }
    if (tid < 15 * 48) {
      const int n = NTOK + tid / 48;
      const int c = (tid % 48) * 4;
      *(u64*)(Xb + n * 200 + c) = 0ull;
    }
  }
  __syncthreads();

  // ---- phase 1: QKV. 12 o-triple tasks over 16 waves. Per k: 4 LDS reads feed 12 MFMAs.
  if (wave < 12) {
    const int p = wave >> 2;     // 0=Q, 1=K, 2=V
    const int o3 = wave & 3;     // which triple of 16-chan tiles
    const u16* wbase = w_bf + p * (CDIM * CDIM) + (o3 * 48 + nl) * CDIM + g * 8;
    floatx4 acc[3][4];
#pragma unroll
    for (int j = 0; j < 3; ++j)
#pragma unroll
      for (int nt = 0; nt < 4; ++nt) acc[j][nt] = (floatx4){0.f, 0.f, 0.f, 0.f};
#pragma unroll
    for (int k = 0; k < 6; ++k) {
      bf16x8 xk[4];
#pragma unroll
      for (int nt = 0; nt < 4; ++nt)
        xk[nt] = *(const bf16x8*)(Xb + (nt * 16 + nl) * 200 + k * 32 + g * 8);
      bf16x8 wf[3];
#pragma unroll
      for (int j = 0; j < 3; ++j)
        wf[j] = *(const bf16x8*)(wbase + j * 16 * CDIM + k * 32);
      if (p < 2) {
#pragma unroll
        for (int j = 0; j < 3; ++j)
#pragma unroll
          for (int nt = 0; nt < 4; ++nt)
            acc[j][nt] = __builtin_amdgcn_mfma_f32_16x16x32_bf16(wf[j], xk[nt], acc[j][nt], 0, 0, 0);
      } else {
#pragma unroll
        for (int j = 0; j < 3; ++j)
#pragma unroll
          for (int nt = 0; nt < 4; ++nt)
            acc[j][nt] = __builtin_amdgcn_mfma_f32_16x16x32_bf16(xk[nt], wf[j], acc[j][nt], 0, 0, 0);
      }
    }
    if (p < 2) {
      u16* dst = (p == 0 ? Qn : Kn);
#pragma unroll
      for (int j = 0; j < 3; ++j)
#pragma unroll
        for (int nt = 0; nt < 4; ++nt)
          st4bf(dst + (nt * 16 + nl) * 200 + (o3 * 48 + j * 16) + g * 4,
                acc[j][nt][0], acc[j][nt][1], acc[j][nt][2], acc[j][nt][3]);
    } else {
#pragma unroll
      for (int j = 0; j < 3; ++j)
#pragma unroll
        for (int nt = 0; nt < 4; ++nt)
          st4bf(Vt + (o3 * 48 + j * 16 + nl) * 72 + nt * 16 + g * 4,
                acc[j][nt][0], acc[j][nt][1], acc[j][nt][2], acc[j][nt][3]);
    }
  }
  __syncthreads();

  // ---- phase 2: l2-normalize Q,K rows (4 lanes per (tensor,head,token))
  {
    const int sub = tid & 3;
    for (int ru = tid >> 2; ru < 2 * HEADS * NTOK; ru += 256) {
      const int t = ru / (HEADS * NTOK);
      const int rem = ru - t * (HEADS * NTOK);
      const int h = rem / NTOK, n = rem - h * NTOK;
      u16* base = (t == 0 ? Qn : Kn) + n * 200 + h * 32 + sub * 8;
      u64 lo = *(u64*)base;
      u64 hi = *(u64*)(base + 4);
      float f[8];
#pragma unroll
      for (int e = 0; e < 4; ++e) f[e] = bf2f((u16)(lo >> (16 * e)));
#pragma unroll
      for (int e = 0; e < 4; ++e) f[4 + e] = bf2f((u16)(hi >> (16 * e)));
      float ss = 0.f;
#pragma unroll
      for (int e = 0; e < 8; ++e) ss += f[e] * f[e];
      ss += __shfl_xor(ss, 1);
      ss += __shfl_xor(ss, 2);
      const float inv = 1.0f / fmaxf(sqrtf(ss), 1e-12f);
      st4bf(base, f[0] * inv, f[1] * inv, f[2] * inv, f[3] * inv);
      st4bf(base + 4, f[4] * inv, f[5] * inv, f[6] * inv, f[7] * inv);
    }
  }
  __syncthreads();

  // ---- phase 3: attention, 24 tasks over 16 waves; exp2 domain (log2e folded)
  {
    const float dl = d_l[b];
    const float LOG2E = 1.442695040888963f;
    const float dl2 = dl * LOG2E;
    const int wmask = b & (NWIN - 1);
    u16* Pb = Pw + wave * (16 * 72);
    for (int t = wave; t < 24; t += 16) {
      const int h = t >> 2, nt2 = t & 3;
      const int n = nt2 * 16 + nl;
      const int ncl = n < NTOK ? n : NTOK - 1;
      const float tdl = temp[h] * dl2;
      const bf16x8 qf = *(const bf16x8*)(Qn + n * 200 + h * 32 + g * 8);
      floatx4 sacc[4];
#pragma unroll
      for (int rt = 0; rt < 4; ++rt) {
        const bf16x8 kf = *(const bf16x8*)(Kn + (rt * 16 + nl) * 200 + h * 32 + g * 8);
        sacc[rt] = __builtin_amdgcn_mfma_f32_16x16x32_bf16(kf, qf, (floatx4){0.f, 0.f, 0.f, 0.f}, 0, 0, 0);
      }
      const float* brow = bias + (h * NTOK + ncl) * NTOK;
      const float* mrow = mask + ((size_t)wmask * NTOK + ncl) * NTOK;
      float L[4][4];
      float pmax = -1e30f;
#pragma unroll
      for (int rt = 0; rt < 3; ++rt) {
        const F4 b4 = *(const F4*)(brow + rt * 16 + g * 4);
        const F4 m4 = *(const F4*)(mrow + rt * 16 + g * 4);
#pragma unroll
        for (int r = 0; r < 4; ++r) {
          const float lv = fmaf(sacc[rt][r], tdl, (b4.f[r] + m4.f[r]) * dl2);
          L[rt][r] = lv;
          pmax = fmaxf(pmax, lv);
        }
      }
      {  // rt=3: only m=48 real (g==0, r==0)
        const float lv48 = fmaf(sacc[3][0], tdl, (brow[48] + mrow[48]) * dl2);
        L[3][0] = L[3][1] = L[3][2] = L[3][3] = -1e30f;
        if (g == 0) { L[3][0] = lv48; pmax = fmaxf(pmax, lv48); }
      }
      pmax = fmaxf(pmax, __shfl_xor(pmax, 16));
      pmax = fmaxf(pmax, __shfl_xor(pmax, 32));
      float psum = 0.f;
#pragma unroll
      for (int rt = 0; rt < 4; ++rt)
#pragma unroll
        for (int r = 0; r < 4; ++r) {
          const float e = exp2f(L[rt][r] - pmax);
          L[rt][r] = e;
          psum += e;
        }
      psum += __shfl_xor(psum, 16);
      psum += __shfl_xor(psum, 32);
      const float rinv = 1.0f / psum;
#pragma unroll
      for (int rt = 0; rt < 4; ++rt)
        st4bf(Pb + nl * 72 + rt * 16 + g * 4,
              L[rt][0] * rinv, L[rt][1] * rinv, L[rt][2] * rinv, L[rt][3] * rinv);
      floatx4 oacc[2];
      oacc[0] = (floatx4){0.f, 0.f, 0.f, 0.f};
      oacc[1] = (floatx4){0.f, 0.f, 0.f, 0.f};
#pragma unroll
      for (int ks = 0; ks < 2; ++ks) {
        const bf16x8 pf = *(const bf16x8*)(Pb + nl * 72 + ks * 32 + g * 8);
#pragma unroll
        for (int dt = 0; dt < 2; ++dt) {
          const bf16x8 vf = *(const bf16x8*)(Vt + (h * 32 + dt * 16 + nl) * 72 + ks * 32 + g * 8);
          oacc[dt] = __builtin_amdgcn_mfma_f32_16x16x32_bf16(vf, pf, oacc[dt], 0, 0, 0);
        }
      }
#pragma unroll
      for (int dt = 0; dt < 2; ++dt)
        st4bf(Xb + n * 200 + h * 32 + dt * 16 + g * 4,
              oacc[dt][0], oacc[dt][1], oacc[dt][2], oacc[dt][3]);
    }
  }
  __syncthreads();

  // ---- phase 4: out = AO @ Wp^T. 4 o-triple tasks; per k: 4 LDS reads feed 12 MFMAs.
  if (wave < 4) {
    float* outb = out + (size_t)b * (NTOK * CDIM);
    const u16* wpb = w_bf + 3 * (CDIM * CDIM);
    const int o3 = wave;
    const u16* wbase = wpb + (o3 * 48 + nl) * CDIM + g * 8;
    floatx4 acc[3][4];
#pragma unroll
    for (int j = 0; j < 3; ++j)
#pragma unroll
      for (int nt = 0; nt < 4; ++nt) acc[j][nt] = (floatx4){0.f, 0.f, 0.f, 0.f};
#pragma unroll
    for (int k = 0; k < 6; ++k) {
      bf16x8 af[4];
#pragma unroll
      for (int nt = 0; nt < 4; ++nt)
        af[nt] = *(const bf16x8*)(Xb + (nt * 16 + nl) * 200 + k * 32 + g * 8);
      bf16x8 wf[3];
#pragma unroll
      for (int j = 0; j < 3; ++j)
        wf[j] = *(const bf16x8*)(wbase + j * 16 * CDIM + k * 32);
#pragma unroll
      for (int j = 0; j < 3; ++j)
#pragma unroll
        for (int nt = 0; nt < 4; ++nt)
          acc[j][nt] = __builtin_amdgcn_mfma_f32_16x16x32_bf16(wf[j], af[nt], acc[j][nt], 0, 0, 0);
    }
#pragma unroll
    for (int j = 0; j < 3; ++j)
#pragma unroll
      for (int nt = 0; nt < 4; ++nt) {
        const int n = nt * 16 + nl;
        if (n < NTOK) {
          float4 v;
          v.x = acc[j][nt][0]; v.y = acc[j][nt][1]; v.z = acc[j][nt][2]; v.w = acc[j][nt][3];
          *(float4*)(outb + n * CDIM + o3 * 48 + j * 16 + g * 4) = v;
        }
      }
  }
}

extern "C" void kernel_launch(void* const* d_in, const int* in_sizes, int n_in,
                              void* d_out, int out_size, void* d_ws, size_t ws_size,
                              hipStream_t stream) {
  const float* x    = (const float*)d_in[0];
  const float* mask = (const float*)d_in[1];
  const float* dl   = (const float*)d_in[2];
  const float* Wq   = (const float*)d_in[3];
  const float* Wk   = (const float*)d_in[4];
  const float* Wv   = (const float*)d_in[5];
  const float* Wp   = (const float*)d_in[6];
  const float* temp = (const float*)d_in[7];
  const float* rpb  = (const float*)d_in[8];
  const int*   rel  = (const int*)d_in[9];

  u16* w_bf = (u16*)d_ws;
  float* bias = (float*)((char*)d_ws + (size_t)4 * CDIM * CDIM * sizeof(u16));
  float* o = (float*)d_out;

  (void)hipFuncSetAttribute((const void*)wattn_main,
                            hipFuncAttributeMaxDynamicSharedMemorySize, LDS_BYTES);

  wprep<<<256, 256, 0, stream>>>(Wq, Wk, Wv, Wp, rpb, rel, w_bf, bias);
  wattn_main<<<8192, 1024, LDS_BYTES, stream>>>(x, mask, dl, temp, w_bf, bias, o);
}

// Round 10
// 590.014 us; speedup vs baseline: 1.3046x; 1.0652x over previous
//
#include <hip/hip_runtime.h>

#define NTOK 49
#define HEADS 6
#define CDIM 192
#define NWIN 4096

typedef unsigned short u16;
typedef unsigned int u32;
typedef unsigned long long u64;
typedef __attribute__((ext_vector_type(8))) __bf16 bf16x8;
typedef __attribute__((ext_vector_type(4))) float floatx4;

struct __attribute__((aligned(4))) F4 { float f[4]; };

// LDS layout (bytes), 12-wave block (768 thr), 1 block/CU.
#define OFF_X 0         // [64][200] u16 (X, later AO)          25600
#define OFF_Q 25600     // [64][200] u16                        25600
#define OFF_K 51200     // [64][200] u16                        25600
#define OFF_V 76800     // [192][72] u16  Vt[chan][tok]         27648
#define OFF_P 104448    // [12 waves][16][72] u16               27648
#define LDS_BYTES 132096

__device__ __forceinline__ u16 f2bf(float f) {
  return __builtin_bit_cast(u16, (__bf16)f);
}
__device__ __forceinline__ void st4bf(u16* p, float a, float b, float c, float d) {
  u32 lo = (u32)f2bf(a) | ((u32)f2bf(b) << 16);
  u32 hi = (u32)f2bf(c) | ((u32)f2bf(d) << 16);
  u64 t = (u64)lo | ((u64)hi << 32);
  *(u64*)p = t;
}
__device__ __forceinline__ float bf2f(u16 u) {
  union { u32 u; float f; } v; v.u = ((u32)u) << 16;
  return v.f;
}

__global__ __launch_bounds__(256)
void wprep(const float* __restrict__ Wq, const float* __restrict__ Wk,
           const float* __restrict__ Wv, const float* __restrict__ Wp,
           const float* __restrict__ rpb, const int* __restrict__ rel,
           u16* __restrict__ w_bf, float* __restrict__ bias) {
  const int tid = blockIdx.x * blockDim.x + threadIdx.x;
  const int stride = gridDim.x * blockDim.x;
  for (int i = tid; i < 4 * CDIM * CDIM; i += stride) {
    const int p = i / (CDIM * CDIM), e = i % (CDIM * CDIM);
    float v = (p == 0) ? Wq[e] : (p == 1) ? Wk[e] : (p == 2) ? Wv[e] : Wp[e];
    w_bf[i] = f2bf(v);
  }
  for (int i = tid; i < HEADS * NTOK * NTOK; i += stride) {
    const int h = i / (NTOK * NTOK), nm = i % (NTOK * NTOK);
    bias[i] = rpb[rel[nm] * HEADS + h];
  }
}

// Fused window attention: 12 waves; phase-1 xf[4][6] register-cached (R1 form),
// phase-3 head-paired tasks with kf cached; balanced task maps (3/2/1 per wave).
__global__ __launch_bounds__(768)
void wattn_main(const float* __restrict__ x, const float* __restrict__ mask,
                const float* __restrict__ d_l, const float* __restrict__ temp,
                const u16* __restrict__ w_bf, const float* __restrict__ bias,
                float* __restrict__ out) {
  extern __shared__ __align__(16) char smem[];
  u16* Xb = (u16*)(smem + OFF_X);
  u16* Qn = (u16*)(smem + OFF_Q);
  u16* Kn = (u16*)(smem + OFF_K);
  u16* Vt = (u16*)(smem + OFF_V);
  u16* Pw = (u16*)(smem + OFF_P);

  const int b = blockIdx.x;
  const int tid = threadIdx.x;
  const int wave = tid >> 6;   // 0..11
  const int lane = tid & 63;
  const int g = lane >> 4;
  const int nl = lane & 15;

  // ---- phase 0: stage x -> bf16 LDS [64][200], zero pad rows 49..63
  {
    const float* xb = x + (size_t)b * (NTOK * CDIM);
    for (int i = tid; i < NTOK * 48; i += 768) {
      const int n = i / 48;
      const int c = (i - n * 48) * 4;
      const float4 v = *(const float4*)(xb + n * CDIM + c);
      st4bf(Xb + n * 200 + c, v.x, v.y, v.z, v.w);
    }
    if (tid < 15 * 48) {
      const int n = NTOK + tid / 48;
      const int c = (tid % 48) * 4;
      *(u64*)(Xb + n * 200 + c) = 0ull;
    }
  }
  __syncthreads();

  // ---- phase 1: QKV, 36 tasks over 12 waves (3 each), xf[4][6] register-cached
  {
    bf16x8 xf[4][6];
#pragma unroll
    for (int nt = 0; nt < 4; ++nt)
#pragma unroll
      for (int k = 0; k < 6; ++k)
        xf[nt][k] = *(const bf16x8*)(Xb + (nt * 16 + nl) * 200 + k * 32 + g * 8);

    for (int u = wave; u < 36; u += 12) {
      const int p = u / 12, o = u % 12;
      const u16* wb = w_bf + p * (CDIM * CDIM) + (o * 16 + nl) * CDIM + g * 8;
      bf16x8 wf[6];
#pragma unroll
      for (int k = 0; k < 6; ++k) wf[k] = *(const bf16x8*)(wb + k * 32);
      floatx4 acc[4];
#pragma unroll
      for (int nt = 0; nt < 4; ++nt) acc[nt] = (floatx4){0.f, 0.f, 0.f, 0.f};
      if (p < 2) {
#pragma unroll
        for (int k = 0; k < 6; ++k)
#pragma unroll
          for (int nt = 0; nt < 4; ++nt)
            acc[nt] = __builtin_amdgcn_mfma_f32_16x16x32_bf16(wf[k], xf[nt][k], acc[nt], 0, 0, 0);
        u16* dst = (p == 0 ? Qn : Kn);
#pragma unroll
        for (int nt = 0; nt < 4; ++nt)
          st4bf(dst + (nt * 16 + nl) * 200 + o * 16 + g * 4,
                acc[nt][0], acc[nt][1], acc[nt][2], acc[nt][3]);
      } else {
#pragma unroll
        for (int k = 0; k < 6; ++k)
#pragma unroll
          for (int nt = 0; nt < 4; ++nt)
            acc[nt] = __builtin_amdgcn_mfma_f32_16x16x32_bf16(xf[nt][k], wf[k], acc[nt], 0, 0, 0);
#pragma unroll
        for (int nt = 0; nt < 4; ++nt)
          st4bf(Vt + (o * 16 + nl) * 72 + nt * 16 + g * 4,
                acc[nt][0], acc[nt][1], acc[nt][2], acc[nt][3]);
      }
    }
  }
  __syncthreads();

  // ---- phase 2: l2-normalize Q,K rows (4 lanes per (tensor,head,token))
  {
    const int sub = tid & 3;
    for (int ru = tid >> 2; ru < 2 * HEADS * NTOK; ru += 192) {
      const int t = ru / (HEADS * NTOK);
      const int rem = ru - t * (HEADS * NTOK);
      const int h = rem / NTOK, n = rem - h * NTOK;
      u16* base = (t == 0 ? Qn : Kn) + n * 200 + h * 32 + sub * 8;
      u64 lo = *(u64*)base;
      u64 hi = *(u64*)(base + 4);
      float f[8];
#pragma unroll
      for (int e = 0; e < 4; ++e) f[e] = bf2f((u16)(lo >> (16 * e)));
#pragma unroll
      for (int e = 0; e < 4; ++e) f[4 + e] = bf2f((u16)(hi >> (16 * e)));
      float ss = 0.f;
#pragma unroll
      for (int e = 0; e < 8; ++e) ss += f[e] * f[e];
      ss += __shfl_xor(ss, 1);
      ss += __shfl_xor(ss, 2);
      const float inv = 1.0f / fmaxf(sqrtf(ss), 1e-12f);
      st4bf(base, f[0] * inv, f[1] * inv, f[2] * inv, f[3] * inv);
      st4bf(base + 4, f[4] * inv, f[5] * inv, f[6] * inv, f[7] * inv);
    }
  }
  __syncthreads();

  // ---- phase 3: attention. Wave w does t = 2w, 2w+1 (same head h=w>>1, kf cached).
  {
    const float dl = d_l[b];
    const float LOG2E = 1.442695040888963f;
    const float dl2 = dl * LOG2E;
    const int wmask = b & (NWIN - 1);
    u16* Pb = Pw + wave * (16 * 72);
    const int h = wave >> 1;
    const float tdl = temp[h] * dl2;
    bf16x8 kf[4];
#pragma unroll
    for (int rt = 0; rt < 4; ++rt)
      kf[rt] = *(const bf16x8*)(Kn + (rt * 16 + nl) * 200 + h * 32 + g * 8);

#pragma unroll
    for (int j = 0; j < 2; ++j) {
      const int nt2 = ((wave & 1) << 1) | j;
      const int n = nt2 * 16 + nl;
      const int ncl = n < NTOK ? n : NTOK - 1;
      const bf16x8 qf = *(const bf16x8*)(Qn + n * 200 + h * 32 + g * 8);
      floatx4 sacc[4];
#pragma unroll
      for (int rt = 0; rt < 4; ++rt)
        sacc[rt] = __builtin_amdgcn_mfma_f32_16x16x32_bf16(kf[rt], qf, (floatx4){0.f, 0.f, 0.f, 0.f}, 0, 0, 0);
      const float* brow = bias + (h * NTOK + ncl) * NTOK;
      const float* mrow = mask + ((size_t)wmask * NTOK + ncl) * NTOK;
      float L[4][4];
      float pmax = -1e30f;
#pragma unroll
      for (int rt = 0; rt < 3; ++rt) {
        const F4 b4 = *(const F4*)(brow + rt * 16 + g * 4);
        const F4 m4 = *(const F4*)(mrow + rt * 16 + g * 4);
#pragma unroll
        for (int r = 0; r < 4; ++r) {
          const float lv = fmaf(sacc[rt][r], tdl, (b4.f[r] + m4.f[r]) * dl2);
          L[rt][r] = lv;
          pmax = fmaxf(pmax, lv);
        }
      }
      {  // rt=3: only m=48 real (g==0, r==0)
        const float lv48 = fmaf(sacc[3][0], tdl, (brow[48] + mrow[48]) * dl2);
        L[3][0] = L[3][1] = L[3][2] = L[3][3] = -1e30f;
        if (g == 0) { L[3][0] = lv48; pmax = fmaxf(pmax, lv48); }
      }
      pmax = fmaxf(pmax, __shfl_xor(pmax, 16));
      pmax = fmaxf(pmax, __shfl_xor(pmax, 32));
      float psum = 0.f;
#pragma unroll
      for (int rt = 0; rt < 4; ++rt)
#pragma unroll
        for (int r = 0; r < 4; ++r) {
          const float e = exp2f(L[rt][r] - pmax);
          L[rt][r] = e;
          psum += e;
        }
      psum += __shfl_xor(psum, 16);
      psum += __shfl_xor(psum, 32);
      const float rinv = 1.0f / psum;
#pragma unroll
      for (int rt = 0; rt < 4; ++rt)
        st4bf(Pb + nl * 72 + rt * 16 + g * 4,
              L[rt][0] * rinv, L[rt][1] * rinv, L[rt][2] * rinv, L[rt][3] * rinv);
      floatx4 oacc[2];
      oacc[0] = (floatx4){0.f, 0.f, 0.f, 0.f};
      oacc[1] = (floatx4){0.f, 0.f, 0.f, 0.f};
#pragma unroll
      for (int ks = 0; ks < 2; ++ks) {
        const bf16x8 pf = *(const bf16x8*)(Pb + nl * 72 + ks * 32 + g * 8);
#pragma unroll
        for (int dt = 0; dt < 2; ++dt) {
          const bf16x8 vf = *(const bf16x8*)(Vt + (h * 32 + dt * 16 + nl) * 72 + ks * 32 + g * 8);
          oacc[dt] = __builtin_amdgcn_mfma_f32_16x16x32_bf16(vf, pf, oacc[dt], 0, 0, 0);
        }
      }
#pragma unroll
      for (int dt = 0; dt < 2; ++dt)
        st4bf(Xb + n * 200 + h * 32 + dt * 16 + g * 4,
              oacc[dt][0], oacc[dt][1], oacc[dt][2], oacc[dt][3]);
    }
  }
  __syncthreads();

  // ---- phase 4: out = AO @ Wp^T, 12 tasks over 12 waves (1 each)
  {
    float* outb = out + (size_t)b * (NTOK * CDIM);
    const u16* wpb = w_bf + 3 * (CDIM * CDIM);
    const int o = wave;
    const u16* wb = wpb + (o * 16 + nl) * CDIM + g * 8;
    floatx4 acc[4];
#pragma unroll
    for (int nt = 0; nt < 4; ++nt) acc[nt] = (floatx4){0.f, 0.f, 0.f, 0.f};
#pragma unroll
    for (int k = 0; k < 6; ++k) {
      const bf16x8 wf = *(const bf16x8*)(wb + k * 32);
#pragma unroll
      for (int nt = 0; nt < 4; ++nt) {
        const bf16x8 af = *(const bf16x8*)(Xb + (nt * 16 + nl) * 200 + k * 32 + g * 8);
        acc[nt] = __builtin_amdgcn_mfma_f32_16x16x32_bf16(wf, af, acc[nt], 0, 0, 0);
      }
    }
#pragma unroll
    for (int nt = 0; nt < 4; ++nt) {
      const int n = nt * 16 + nl;
      if (n < NTOK) {
        float4 v;
        v.x = acc[nt][0]; v.y = acc[nt][1]; v.z = acc[nt][2]; v.w = acc[nt][3];
        *(float4*)(outb + n * CDIM + o * 16 + g * 4) = v;
      }
    }
  }
}

extern "C" void kernel_launch(void* const* d_in, const int* in_sizes, int n_in,
                              void* d_out, int out_size, void* d_ws, size_t ws_size,
                              hipStream_t stream) {
  const float* x    = (const float*)d_in[0];
  const float* mask = (const float*)d_in[1];
  const float* dl   = (const float*)d_in[2];
  const float* Wq   = (const float*)d_in[3];
  const float* Wk   = (const float*)d_in[4];
  const float* Wv   = (const float*)d_in[5];
  const float* Wp   = (const float*)d_in[6];
  const float* temp = (const float*)d_in[7];
  const float* rpb  = (const float*)d_in[8];
  const int*   rel  = (const int*)d_in[9];

  u16* w_bf = (u16*)d_ws;
  float* bias = (float*)((char*)d_ws + (size_t)4 * CDIM * CDIM * sizeof(u16));
  float* o = (float*)d_out;

  (void)hipFuncSetAttribute((const void*)wattn_main,
                            hipFuncAttributeMaxDynamicSharedMemorySize, LDS_BYTES);

  wprep<<<256, 256, 0, stream>>>(Wq, Wk, Wv, Wp, rpb, rel, w_bf, bias);
  wattn_main<<<8192, 768, LDS_BYTES, stream>>>(x, mask, dl, temp, w_bf, bias, o);
}

// Round 11
// 549.380 us; speedup vs baseline: 1.4011x; 1.0740x over previous
//
#include <hip/hip_runtime.h>

#define NTOK 49
#define HEADS 6
#define CDIM 192
#define NWIN 4096

typedef unsigned short u16;
typedef unsigned int u32;
typedef unsigned long long u64;
typedef __attribute__((ext_vector_type(8))) __bf16 bf16x8;
typedef __attribute__((ext_vector_type(4))) float floatx4;
typedef __attribute__((ext_vector_type(4))) u32 u32x4;

struct __attribute__((aligned(4))) F4 { float f[4]; };

// LDS layout (bytes), 16-wave block (1024 thr), 1 block/CU.
#define OFF_X 0         // [64][200] u16 (X, later AO)          25600
#define OFF_Q 25600     // [64][200] u16 (raw Q)                25600
#define OFF_K 51200     // [64][200] u16 (raw K)                25600
#define OFF_V 76800     // [192][72] u16  Vt[chan][tok]         27648
#define OFF_P 104448    // [16 waves][16][72] u16               36864
#define OFF_N 141312    // [16 waves][128] f32 (krec|qrec)       8192
#define LDS_BYTES 149504

// HW bf16 convert (RNE).
__device__ __forceinline__ u16 f2bf(float f) {
  return __builtin_bit_cast(u16, (__bf16)f);
}
__device__ __forceinline__ void st4bf(u16* p, float a, float b, float c, float d) {
  u32 lo = (u32)f2bf(a) | ((u32)f2bf(b) << 16);
  u32 hi = (u32)f2bf(c) | ((u32)f2bf(d) << 16);
  u64 t = (u64)lo | ((u64)hi << 32);
  *(u64*)p = t;
}
__device__ __forceinline__ float bflo(u32 u) {
  union { u32 u; float f; } v; v.u = u << 16;
  return v.f;
}
__device__ __forceinline__ float bfhi(u32 u) {
  union { u32 u; float f; } v; v.u = u & 0xffff0000u;
  return v.f;
}

__global__ __launch_bounds__(256)
void wprep(const float* __restrict__ Wq, const float* __restrict__ Wk,
           const float* __restrict__ Wv, const float* __restrict__ Wp,
           const float* __restrict__ rpb, const int* __restrict__ rel,
           u16* __restrict__ w_bf, float* __restrict__ bias) {
  const int tid = blockIdx.x * blockDim.x + threadIdx.x;
  const int stride = gridDim.x * blockDim.x;
  for (int i = tid; i < 4 * CDIM * CDIM; i += stride) {
    const int p = i / (CDIM * CDIM), e = i % (CDIM * CDIM);
    float v = (p == 0) ? Wq[e] : (p == 1) ? Wk[e] : (p == 2) ? Wv[e] : Wp[e];
    w_bf[i] = f2bf(v);
  }
  for (int i = tid; i < HEADS * NTOK * NTOK; i += stride) {
    const int h = i / (NTOK * NTOK), nm = i % (NTOK * NTOK);
    bias[i] = rpb[rel[nm] * HEADS + h];
  }
}

// Fused window attention: R7 structure minus the l2-norm phase (folded into softmax).
// 16 waves, 3 barriers. Phase-3 tasks paired per head (kf cached once per wave).
__global__ __launch_bounds__(1024)
void wattn_main(const float* __restrict__ x, const float* __restrict__ mask,
                const float* __restrict__ d_l, const float* __restrict__ temp,
                const u16* __restrict__ w_bf, const float* __restrict__ bias,
                float* __restrict__ out) {
  extern __shared__ __align__(16) char smem[];
  u16* Xb = (u16*)(smem + OFF_X);
  u16* Qn = (u16*)(smem + OFF_Q);
  u16* Kn = (u16*)(smem + OFF_K);
  u16* Vt = (u16*)(smem + OFF_V);
  u16* Pw = (u16*)(smem + OFF_P);

  const int b = blockIdx.x;
  const int tid = threadIdx.x;
  const int wave = tid >> 6;   // 0..15
  const int lane = tid & 63;
  const int g = lane >> 4;
  const int nl = lane & 15;

  // ---- phase 0: stage x -> bf16 LDS [64][200], zero pad rows 49..63
  {
    const float* xb = x + (size_t)b * (NTOK * CDIM);
    for (int i = tid; i < NTOK * 48; i += 1024) {
      const int n = i / 48;
      const int c = (i - n * 48) * 4;
      const float4 v = *(const float4*)(xb + n * CDIM + c);
      st4bf(Xb + n * 200 + c, v.x, v.y, v.z, v.w);
    }
    if (tid < 15 * 48) {
      const int n = NTOK + tid / 48;
      const int c = (tid % 48) * 4;
      *(u64*)(Xb + n * 200 + c) = 0ull;
    }
  }
  __syncthreads();

  // ---- phase 1: QKV projections, 36 tasks over 16 waves, per-k fragment loads (R7 form)
  for (int u = wave; u < 36; u += 16) {
    const int p = u / 12, o = u % 12;
    const u16* wb = w_bf + p * (CDIM * CDIM) + (o * 16 + nl) * CDIM + g * 8;
    floatx4 acc[4];
#pragma unroll
    for (int nt = 0; nt < 4; ++nt) acc[nt] = (floatx4){0.f, 0.f, 0.f, 0.f};
    if (p < 2) {
#pragma unroll
      for (int k = 0; k < 6; ++k) {
        const bf16x8 wf = *(const bf16x8*)(wb + k * 32);
#pragma unroll
        for (int nt = 0; nt < 4; ++nt) {
          const bf16x8 xk = *(const bf16x8*)(Xb + (nt * 16 + nl) * 200 + k * 32 + g * 8);
          acc[nt] = __builtin_amdgcn_mfma_f32_16x16x32_bf16(wf, xk, acc[nt], 0, 0, 0);
        }
      }
      u16* dst = (p == 0 ? Qn : Kn);
#pragma unroll
      for (int nt = 0; nt < 4; ++nt)
        st4bf(dst + (nt * 16 + nl) * 200 + o * 16 + g * 4,
              acc[nt][0], acc[nt][1], acc[nt][2], acc[nt][3]);
    } else {
#pragma unroll
      for (int k = 0; k < 6; ++k) {
        const bf16x8 wf = *(const bf16x8*)(wb + k * 32);
#pragma unroll
        for (int nt = 0; nt < 4; ++nt) {
          const bf16x8 xk = *(const bf16x8*)(Xb + (nt * 16 + nl) * 200 + k * 32 + g * 8);
          acc[nt] = __builtin_amdgcn_mfma_f32_16x16x32_bf16(xk, wf, acc[nt], 0, 0, 0);
        }
      }
#pragma unroll
      for (int nt = 0; nt < 4; ++nt)
        st4bf(Vt + (o * 16 + nl) * 72 + nt * 16 + g * 4,
              acc[nt][0], acc[nt][1], acc[nt][2], acc[nt][3]);
    }
  }
  __syncthreads();

  // ---- phase 3: attention with folded l2-norm. Waves 0-7: t={2w,2w+1} (one head);
  //      waves 8-15: t={w+8}. exp2 domain, log2e folded into scales.
  {
    const float dl = d_l[b];
    const float LOG2E = 1.442695040888963f;
    const float dl2 = dl * LOG2E;
    const int wmask = b & (NWIN - 1);
    u16* Pb = Pw + wave * (16 * 72);
    float* nrmw = (float*)(smem + OFF_N) + wave * 128;

    int t0, ntask;
    if (wave < 8) { t0 = wave * 2; ntask = 2; }
    else          { t0 = wave + 8; ntask = 1; }
    const int h = t0 >> 2;

    // per-wave norms for head h: lane = token; same-wave LDS write->read (no barrier)
    {
      float ssk = 0.f, ssq = 0.f;
      const u16* krow = Kn + lane * 200 + h * 32;
      const u16* qrow = Qn + lane * 200 + h * 32;
#pragma unroll
      for (int j4 = 0; j4 < 4; ++j4) {
        const u32x4 kk = *(const u32x4*)(krow + j4 * 8);
        const u32x4 qq = *(const u32x4*)(qrow + j4 * 8);
#pragma unroll
        for (int e = 0; e < 4; ++e) {
          const float k0 = bflo(kk[e]), k1 = bfhi(kk[e]);
          const float q0 = bflo(qq[e]), q1 = bfhi(qq[e]);
          ssk = fmaf(k0, k0, fmaf(k1, k1, ssk));
          ssq = fmaf(q0, q0, fmaf(q1, q1, ssq));
        }
      }
      nrmw[lane] = 1.f / fmaxf(sqrtf(ssk), 1e-12f);
      nrmw[64 + lane] = 1.f / fmaxf(sqrtf(ssq), 1e-12f);
    }

    const float tdl = temp[h] * dl2;
    bf16x8 kf[4];
#pragma unroll
    for (int rt = 0; rt < 4; ++rt)
      kf[rt] = *(const bf16x8*)(Kn + (rt * 16 + nl) * 200 + h * 32 + g * 8);

    for (int j = 0; j < ntask; ++j) {
      const int t = t0 + j;
      const int nt2 = t & 3;
      const int n = nt2 * 16 + nl;
      const int ncl = n < NTOK ? n : NTOK - 1;
      const bf16x8 qf = *(const bf16x8*)(Qn + n * 200 + h * 32 + g * 8);
      floatx4 sacc[4];
#pragma unroll
      for (int rt = 0; rt < 4; ++rt)
        sacc[rt] = __builtin_amdgcn_mfma_f32_16x16x32_bf16(kf[rt], qf, (floatx4){0.f, 0.f, 0.f, 0.f}, 0, 0, 0);
      const float qr2 = nrmw[64 + n] * tdl;
      const float* brow = bias + (h * NTOK + ncl) * NTOK;
      const float* mrow = mask + ((size_t)wmask * NTOK + ncl) * NTOK;
      float L[4][4];
      float pmax = -1e30f;
#pragma unroll
      for (int rt = 0; rt < 3; ++rt) {
        const F4 b4 = *(const F4*)(brow + rt * 16 + g * 4);
        const F4 m4 = *(const F4*)(mrow + rt * 16 + g * 4);
        const F4 kr = *(const F4*)(nrmw + rt * 16 + g * 4);
#pragma unroll
        for (int r = 0; r < 4; ++r) {
          const float lv = fmaf(sacc[rt][r] * kr.f[r], qr2, (b4.f[r] + m4.f[r]) * dl2);
          L[rt][r] = lv;
          pmax = fmaxf(pmax, lv);
        }
      }
      {  // rt=3: only m=48 real (g==0, r==0)
        const float lv48 = fmaf(sacc[3][0] * nrmw[48], qr2, (brow[48] + mrow[48]) * dl2);
        L[3][0] = L[3][1] = L[3][2] = L[3][3] = -1e30f;
        if (g == 0) { L[3][0] = lv48; pmax = fmaxf(pmax, lv48); }
      }
      pmax = fmaxf(pmax, __shfl_xor(pmax, 16));
      pmax = fmaxf(pmax, __shfl_xor(pmax, 32));
      float psum = 0.f;
#pragma unroll
      for (int rt = 0; rt < 4; ++rt)
#pragma unroll
        for (int r = 0; r < 4; ++r) {
          const float e = exp2f(L[rt][r] - pmax);
          L[rt][r] = e;
          psum += e;
        }
      psum += __shfl_xor(psum, 16);
      psum += __shfl_xor(psum, 32);
      const float rinv = 1.0f / psum;
#pragma unroll
      for (int rt = 0; rt < 4; ++rt)
        st4bf(Pb + nl * 72 + rt * 16 + g * 4,
              L[rt][0] * rinv, L[rt][1] * rinv, L[rt][2] * rinv, L[rt][3] * rinv);
      floatx4 oacc[2];
      oacc[0] = (floatx4){0.f, 0.f, 0.f, 0.f};
      oacc[1] = (floatx4){0.f, 0.f, 0.f, 0.f};
#pragma unroll
      for (int ks = 0; ks < 2; ++ks) {
        const bf16x8 pf = *(const bf16x8*)(Pb + nl * 72 + ks * 32 + g * 8);
#pragma unroll
        for (int dt = 0; dt < 2; ++dt) {
          const bf16x8 vf = *(const bf16x8*)(Vt + (h * 32 + dt * 16 + nl) * 72 + ks * 32 + g * 8);
          oacc[dt] = __builtin_amdgcn_mfma_f32_16x16x32_bf16(vf, pf, oacc[dt], 0, 0, 0);
        }
      }
#pragma unroll
      for (int dt = 0; dt < 2; ++dt)
        st4bf(Xb + n * 200 + h * 32 + dt * 16 + g * 4,
              oacc[dt][0], oacc[dt][1], oacc[dt][2], oacc[dt][3]);
    }
  }
  __syncthreads();

  // ---- phase 4: out = AO @ Wp^T (out^T = Wp * AO^T), 12 tasks over 16 waves (R7 form)
  {
    float* outb = out + (size_t)b * (NTOK * CDIM);
    const u16* wpb = w_bf + 3 * (CDIM * CDIM);
    for (int o = wave; o < 12; o += 16) {
      const u16* wb = wpb + (o * 16 + nl) * CDIM + g * 8;
      floatx4 acc[4];
#pragma unroll
      for (int nt = 0; nt < 4; ++nt) acc[nt] = (floatx4){0.f, 0.f, 0.f, 0.f};
#pragma unroll
      for (int k = 0; k < 6; ++k) {
        const bf16x8 wf = *(const bf16x8*)(wb + k * 32);
#pragma unroll
        for (int nt = 0; nt < 4; ++nt) {
          const bf16x8 af = *(const bf16x8*)(Xb + (nt * 16 + nl) * 200 + k * 32 + g * 8);
          acc[nt] = __builtin_amdgcn_mfma_f32_16x16x32_bf16(wf, af, acc[nt], 0, 0, 0);
        }
      }
#pragma unroll
      for (int nt = 0; nt < 4; ++nt) {
        const int n = nt * 16 + nl;
        if (n < NTOK) {
          float4 v;
          v.x = acc[nt][0]; v.y = acc[nt][1]; v.z = acc[nt][2]; v.w = acc[nt][3];
          *(float4*)(outb + n * CDIM + o * 16 + g * 4) = v;
        }
      }
    }
  }
}

extern "C" void kernel_launch(void* const* d_in, const int* in_sizes, int n_in,
                              void* d_out, int out_size, void* d_ws, size_t ws_size,
                              hipStream_t stream) {
  const float* x    = (const float*)d_in[0];
  const float* mask = (const float*)d_in[1];
  const float* dl   = (const float*)d_in[2];
  const float* Wq   = (const float*)d_in[3];
  const float* Wk   = (const float*)d_in[4];
  const float* Wv   = (const float*)d_in[5];
  const float* Wp   = (const float*)d_in[6];
  const float* temp = (const float*)d_in[7];
  const float* rpb  = (const float*)d_in[8];
  const int*   rel  = (const int*)d_in[9];

  u16* w_bf = (u16*)d_ws;
  float* bias = (float*)((char*)d_ws + (size_t)4 * CDIM * CDIM * sizeof(u16));
  float* o = (float*)d_out;

  (void)hipFuncSetAttribute((const void*)wattn_main,
                            hipFuncAttributeMaxDynamicSharedMemorySize, LDS_BYTES);

  wprep<<<256, 256, 0, stream>>>(Wq, Wk, Wv, Wp, rpb, rel, w_bf, bias);
  wattn_main<<<8192, 1024, LDS_BYTES, stream>>>(x, mask, dl, temp, w_bf, bias, o);
}

// Round 12
// 537.116 us; speedup vs baseline: 1.4331x; 1.0228x over previous
//
#include <hip/hip_runtime.h>

#define NTOK 49
#define HEADS 6
#define CDIM 192
#define NWIN 4096

typedef unsigned short u16;
typedef unsigned int u32;
typedef unsigned long long u64;
typedef __attribute__((ext_vector_type(8))) __bf16 bf16x8;
typedef __attribute__((ext_vector_type(4))) float floatx4;

struct __attribute__((aligned(4))) F4 { float f[4]; };

// LDS layout (bytes), 16-wave block (1024 thr), 1 block/CU.
#define OFF_X 0         // [64][200] u16 (X, later AO)          25600
#define OFF_Q 25600     // [64][200] u16 (raw Q)                25600
#define OFF_K 51200     // [64][200] u16 (raw K)                25600
#define OFF_V 76800     // [192][72] u16  Vt[chan][tok]         27648
#define OFF_P 104448    // [16 waves][16][72] u16               36864
#define OFF_N 141312    // [16 waves][128] f32 (krec|qrec)       8192
#define OFF_NP 149504   // [2][12][64] f32 partial sumsq         6144
#define LDS_BYTES 155648

// HW bf16 convert (RNE).
__device__ __forceinline__ u16 f2bf(float f) {
  return __builtin_bit_cast(u16, (__bf16)f);
}
__device__ __forceinline__ void st4bf(u16* p, float a, float b, float c, float d) {
  u32 lo = (u32)f2bf(a) | ((u32)f2bf(b) << 16);
  u32 hi = (u32)f2bf(c) | ((u32)f2bf(d) << 16);
  u64 t = (u64)lo | ((u64)hi << 32);
  *(u64*)p = t;
}

__global__ __launch_bounds__(256)
void wprep(const float* __restrict__ Wq, const float* __restrict__ Wk,
           const float* __restrict__ Wv, const float* __restrict__ Wp,
           const float* __restrict__ rpb, const int* __restrict__ rel,
           u16* __restrict__ w_bf, float* __restrict__ bias) {
  const int tid = blockIdx.x * blockDim.x + threadIdx.x;
  const int stride = gridDim.x * blockDim.x;
  for (int i = tid; i < 4 * CDIM * CDIM; i += stride) {
    const int p = i / (CDIM * CDIM), e = i % (CDIM * CDIM);
    float v = (p == 0) ? Wq[e] : (p == 1) ? Wk[e] : (p == 2) ? Wv[e] : Wp[e];
    w_bf[i] = f2bf(v);
  }
  for (int i = tid; i < HEADS * NTOK * NTOK; i += stride) {
    const int h = i / (NTOK * NTOK), nm = i % (NTOK * NTOK);
    bias[i] = rpb[rel[nm] * HEADS + h];
  }
}

// Fused window attention: R11 structure + norms as phase-1 byproducts (f32 partial
// sumsq via shuffle reduce) + softmax without max-subtraction (inputs bounded).
__global__ __launch_bounds__(1024)
void wattn_main(const float* __restrict__ x, const float* __restrict__ mask,
                const float* __restrict__ d_l, const float* __restrict__ temp,
                const u16* __restrict__ w_bf, const float* __restrict__ bias,
                float* __restrict__ out) {
  extern __shared__ __align__(16) char smem[];
  u16* Xb = (u16*)(smem + OFF_X);
  u16* Qn = (u16*)(smem + OFF_Q);
  u16* Kn = (u16*)(smem + OFF_K);
  u16* Vt = (u16*)(smem + OFF_V);
  u16* Pw = (u16*)(smem + OFF_P);
  float* NP = (float*)(smem + OFF_NP);  // [2][12][64] partial sumsq (p: 0=Q,1=K)

  const int b = blockIdx.x;
  const int tid = threadIdx.x;
  const int wave = tid >> 6;   // 0..15
  const int lane = tid & 63;
  const int g = lane >> 4;
  const int nl = lane & 15;

  // ---- phase 0: stage x -> bf16 LDS [64][200], zero pad rows 49..63
  {
    const float* xb = x + (size_t)b * (NTOK * CDIM);
    for (int i = tid; i < NTOK * 48; i += 1024) {
      const int n = i / 48;
      const int c = (i - n * 48) * 4;
      const float4 v = *(const float4*)(xb + n * CDIM + c);
      st4bf(Xb + n * 200 + c, v.x, v.y, v.z, v.w);
    }
    if (tid < 15 * 48) {
      const int n = NTOK + tid / 48;
      const int c = (tid % 48) * 4;
      *(u64*)(Xb + n * 200 + c) = 0ull;
    }
  }
  __syncthreads();

  // ---- phase 1: QKV, 36 tasks over 16 waves; Q/K tasks also emit f32 sumsq partials
  for (int u = wave; u < 36; u += 16) {
    const int p = u / 12, o = u % 12;
    const u16* wb = w_bf + p * (CDIM * CDIM) + (o * 16 + nl) * CDIM + g * 8;
    floatx4 acc[4];
#pragma unroll
    for (int nt = 0; nt < 4; ++nt) acc[nt] = (floatx4){0.f, 0.f, 0.f, 0.f};
    if (p < 2) {
#pragma unroll
      for (int k = 0; k < 6; ++k) {
        const bf16x8 wf = *(const bf16x8*)(wb + k * 32);
#pragma unroll
        for (int nt = 0; nt < 4; ++nt) {
          const bf16x8 xk = *(const bf16x8*)(Xb + (nt * 16 + nl) * 200 + k * 32 + g * 8);
          acc[nt] = __builtin_amdgcn_mfma_f32_16x16x32_bf16(wf, xk, acc[nt], 0, 0, 0);
        }
      }
      u16* dst = (p == 0 ? Qn : Kn);
      float* np = NP + (p * 12 + o) * 64;
#pragma unroll
      for (int nt = 0; nt < 4; ++nt) {
        st4bf(dst + (nt * 16 + nl) * 200 + o * 16 + g * 4,
              acc[nt][0], acc[nt][1], acc[nt][2], acc[nt][3]);
        // partial sum of squares over this 16-chan slice for token nt*16+nl
        float s = acc[nt][0] * acc[nt][0];
        s = fmaf(acc[nt][1], acc[nt][1], s);
        s = fmaf(acc[nt][2], acc[nt][2], s);
        s = fmaf(acc[nt][3], acc[nt][3], s);
        s += __shfl_xor(s, 16);
        s += __shfl_xor(s, 32);
        if (g == 0) np[nt * 16 + nl] = s;
      }
    } else {
#pragma unroll
      for (int k = 0; k < 6; ++k) {
        const bf16x8 wf = *(const bf16x8*)(wb + k * 32);
#pragma unroll
        for (int nt = 0; nt < 4; ++nt) {
          const bf16x8 xk = *(const bf16x8*)(Xb + (nt * 16 + nl) * 200 + k * 32 + g * 8);
          acc[nt] = __builtin_amdgcn_mfma_f32_16x16x32_bf16(xk, wf, acc[nt], 0, 0, 0);
        }
      }
#pragma unroll
      for (int nt = 0; nt < 4; ++nt)
        st4bf(Vt + (o * 16 + nl) * 72 + nt * 16 + g * 4,
              acc[nt][0], acc[nt][1], acc[nt][2], acc[nt][3]);
    }
  }
  __syncthreads();

  // ---- phase 3: attention with folded l2-norm (no max-subtraction; inputs bounded).
  //      Waves 0-7: t={2w,2w+1} (one head); waves 8-15: t={w+8}.
  {
    const float dl = d_l[b];
    const float LOG2E = 1.442695040888963f;
    const float dl2 = dl * LOG2E;
    const int wmask = b & (NWIN - 1);
    u16* Pb = Pw + wave * (16 * 72);
    float* nrmw = (float*)(smem + OFF_N) + wave * 128;

    int t0, ntask;
    if (wave < 8) { t0 = wave * 2; ntask = 2; }
    else          { t0 = wave + 8; ntask = 1; }
    const int h = t0 >> 2;

    // combine partials -> reciprocal norms (lane = token; coalesced f32 reads)
    {
      const float kss = NP[(12 + 2 * h) * 64 + lane] + NP[(12 + 2 * h + 1) * 64 + lane];
      const float qss = NP[(2 * h) * 64 + lane] + NP[(2 * h + 1) * 64 + lane];
      nrmw[lane] = 1.f / fmaxf(sqrtf(kss), 1e-12f);
      nrmw[64 + lane] = 1.f / fmaxf(sqrtf(qss), 1e-12f);
    }

    const float tdl = temp[h] * dl2;
    bf16x8 kf[4];
#pragma unroll
    for (int rt = 0; rt < 4; ++rt)
      kf[rt] = *(const bf16x8*)(Kn + (rt * 16 + nl) * 200 + h * 32 + g * 8);

    for (int j = 0; j < ntask; ++j) {
      const int t = t0 + j;
      const int nt2 = t & 3;
      const int n = nt2 * 16 + nl;
      const int ncl = n < NTOK ? n : NTOK - 1;
      const bf16x8 qf = *(const bf16x8*)(Qn + n * 200 + h * 32 + g * 8);
      floatx4 sacc[4];
#pragma unroll
      for (int rt = 0; rt < 4; ++rt)
        sacc[rt] = __builtin_amdgcn_mfma_f32_16x16x32_bf16(kf[rt], qf, (floatx4){0.f, 0.f, 0.f, 0.f}, 0, 0, 0);
      const float qr2 = nrmw[64 + n] * tdl;
      const float* brow = bias + (h * NTOK + ncl) * NTOK;
      const float* mrow = mask + ((size_t)wmask * NTOK + ncl) * NTOK;
      float L[4][4];
#pragma unroll
      for (int rt = 0; rt < 3; ++rt) {
        const F4 b4 = *(const F4*)(brow + rt * 16 + g * 4);
        const F4 m4 = *(const F4*)(mrow + rt * 16 + g * 4);
        const F4 kr = *(const F4*)(nrmw + rt * 16 + g * 4);
#pragma unroll
        for (int r = 0; r < 4; ++r)
          L[rt][r] = fmaf(sacc[rt][r] * kr.f[r], qr2, (b4.f[r] + m4.f[r]) * dl2);
      }
      {  // rt=3: only m=48 real (g==0, r==0)
        const float lv48 = fmaf(sacc[3][0] * nrmw[48], qr2, (brow[48] + mrow[48]) * dl2);
        L[3][0] = L[3][1] = L[3][2] = L[3][3] = -1e30f;
        if (g == 0) L[3][0] = lv48;
      }
      float psum = 0.f;
#pragma unroll
      for (int rt = 0; rt < 4; ++rt)
#pragma unroll
        for (int r = 0; r < 4; ++r) {
          const float e = exp2f(L[rt][r]);
          L[rt][r] = e;
          psum += e;
        }
      psum += __shfl_xor(psum, 16);
      psum += __shfl_xor(psum, 32);
      const float rinv = 1.0f / psum;
#pragma unroll
      for (int rt = 0; rt < 4; ++rt)
        st4bf(Pb + nl * 72 + rt * 16 + g * 4,
              L[rt][0] * rinv, L[rt][1] * rinv, L[rt][2] * rinv, L[rt][3] * rinv);
      floatx4 oacc[2];
      oacc[0] = (floatx4){0.f, 0.f, 0.f, 0.f};
      oacc[1] = (floatx4){0.f, 0.f, 0.f, 0.f};
#pragma unroll
      for (int ks = 0; ks < 2; ++ks) {
        const bf16x8 pf = *(const bf16x8*)(Pb + nl * 72 + ks * 32 + g * 8);
#pragma unroll
        for (int dt = 0; dt < 2; ++dt) {
          const bf16x8 vf = *(const bf16x8*)(Vt + (h * 32 + dt * 16 + nl) * 72 + ks * 32 + g * 8);
          oacc[dt] = __builtin_amdgcn_mfma_f32_16x16x32_bf16(vf, pf, oacc[dt], 0, 0, 0);
        }
      }
#pragma unroll
      for (int dt = 0; dt < 2; ++dt)
        st4bf(Xb + n * 200 + h * 32 + dt * 16 + g * 4,
              oacc[dt][0], oacc[dt][1], oacc[dt][2], oacc[dt][3]);
    }
  }
  __syncthreads();

  // ---- phase 4: out = AO @ Wp^T (out^T = Wp * AO^T), 12 tasks over 16 waves
  {
    float* outb = out + (size_t)b * (NTOK * CDIM);
    const u16* wpb = w_bf + 3 * (CDIM * CDIM);
    for (int o = wave; o < 12; o += 16) {
      const u16* wb = wpb + (o * 16 + nl) * CDIM + g * 8;
      floatx4 acc[4];
#pragma unroll
      for (int nt = 0; nt < 4; ++nt) acc[nt] = (floatx4){0.f, 0.f, 0.f, 0.f};
#pragma unroll
      for (int k = 0; k < 6; ++k) {
        const bf16x8 wf = *(const bf16x8*)(wb + k * 32);
#pragma unroll
        for (int nt = 0; nt < 4; ++nt) {
          const bf16x8 af = *(const bf16x8*)(Xb + (nt * 16 + nl) * 200 + k * 32 + g * 8);
          acc[nt] = __builtin_amdgcn_mfma_f32_16x16x32_bf16(wf, af, acc[nt], 0, 0, 0);
        }
      }
#pragma unroll
      for (int nt = 0; nt < 4; ++nt) {
        const int n = nt * 16 + nl;
        if (n < NTOK) {
          float4 v;
          v.x = acc[nt][0]; v.y = acc[nt][1]; v.z = acc[nt][2]; v.w = acc[nt][3];
          *(float4*)(outb + n * CDIM + o * 16 + g * 4) = v;
        }
      }
    }
  }
}

extern "C" void kernel_launch(void* const* d_in, const int* in_sizes, int n_in,
                              void* d_out, int out_size, void* d_ws, size_t ws_size,
                              hipStream_t stream) {
  const float* x    = (const float*)d_in[0];
  const float* mask = (const float*)d_in[1];
  const float* dl   = (const float*)d_in[2];
  const float* Wq   = (const float*)d_in[3];
  const float* Wk   = (const float*)d_in[4];
  const float* Wv   = (const float*)d_in[5];
  const float* Wp   = (const float*)d_in[6];
  const float* temp = (const float*)d_in[7];
  const float* rpb  = (const float*)d_in[8];
  const int*   rel  = (const int*)d_in[9];

  u16* w_bf = (u16*)d_ws;
  float* bias = (float*)((char*)d_ws + (size_t)4 * CDIM * CDIM * sizeof(u16));
  float* o = (float*)d_out;

  (void)hipFuncSetAttribute((const void*)wattn_main,
                            hipFuncAttributeMaxDynamicSharedMemorySize, LDS_BYTES);

  wprep<<<256, 256, 0, stream>>>(Wq, Wk, Wv, Wp, rpb, rel, w_bf, bias);
  wattn_main<<<8192, 1024, LDS_BYTES, stream>>>(x, mask, dl, temp, w_bf, bias, o);
}